// Round 6
// baseline (258.605 us; speedup 1.0000x reference)
//
#include <hip/hip_runtime.h>

#define B_  4
#define T_  2048
#define H_  16
#define DM_ 1024
#define DH_ 64
#define RK_ 32

using u16 = unsigned short;
using u32 = unsigned int;
typedef float  floatx4 __attribute__((ext_vector_type(4)));
typedef __bf16 bf16x8  __attribute__((ext_vector_type(8)));
typedef u16    u16x8   __attribute__((ext_vector_type(8)));
typedef u16    u16x4   __attribute__((ext_vector_type(4)));
typedef short  s16x4   __attribute__((ext_vector_type(4)));

#define MFMA16(a,b,c) __builtin_amdgcn_mfma_f32_16x16x32_bf16((a),(b),(c),0,0,0)
// K=16 bf16 MFMA: A/B frag = 4 bf16 (k = quad*4+j), C/D same 16x16 layout
#define MFMA1K(a,b,c) __builtin_amdgcn_mfma_f32_16x16x16bf16_1k((a),(b),(c),0,0,0)

__device__ __forceinline__ u16 f2bf(float f) {
  unsigned u = __float_as_uint(f);
  u += 0x7fffu + ((u >> 16) & 1u);   // RNE
  return (u16)(u >> 16);
}
// RNE pack: (bf16(b)<<16)|bf16(a)
__device__ __forceinline__ u32 pack_bf(float a, float b) {
  u32 ua = __float_as_uint(a); ua += 0x7fffu + ((ua >> 16) & 1u);
  u32 ub = __float_as_uint(b); ub += 0x7fffu + ((ub >> 16) & 1u);
  return __builtin_amdgcn_perm(ub, ua, 0x07060302u);
}
// truncation pack (1 instr) — for P in the hot loop (values > 0)
__device__ __forceinline__ u32 tpack(float a, float b) {
  return __builtin_amdgcn_perm(__float_as_uint(b), __float_as_uint(a), 0x07060302u);
}

// async global->LDS, 16B per lane. LDS dest is wave-uniform base; HW adds lane*16.
__device__ __forceinline__ void async_copy16(const u16* g, const u16* lds_uniform_base) {
  __builtin_amdgcn_global_load_lds(
      (const __attribute__((address_space(1))) unsigned int*)(unsigned long long)g,
      (__attribute__((address_space(3))) unsigned int*)(unsigned int)(unsigned long long)lds_uniform_base,
      16, 0, 0);
}

// ---------------- conversion kernels ----------------
__global__ __launch_bounds__(256) void cvt_x(const float* __restrict__ s,
                                             u16* __restrict__ d, int n4) {
  int i = blockIdx.x * 256 + threadIdx.x;
  if (i >= n4) return;
  float4 v = reinterpret_cast<const float4*>(s)[i];
  u16x4 o = { f2bf(v.x), f2bf(v.y), f2bf(v.z), f2bf(v.w) };
  reinterpret_cast<u16x4*>(d)[i] = o;
}

// Wv -> Wcat rows [0,1024); Wo -> Wcat rows [2048,3072)
__global__ __launch_bounds__(256) void cvt_wvo(const float* __restrict__ Wv,
                                               const float* __restrict__ Wo,
                                               u16* __restrict__ Wcat) {
  int i = blockIdx.x * 256 + threadIdx.x;       // 2 x 262144 float4-groups
  int reg = i >> 18;
  const float* s = reg ? Wo : Wv;
  int j = i & 262143;
  float4 v = reinterpret_cast<const float4*>(s)[j];
  u16x4 o = { f2bf(v.x), f2bf(v.y), f2bf(v.z), f2bf(v.w) };
  reinterpret_cast<u16x4*>(Wcat)[(reg ? 524288 : 0) + j] = o;
}

// ---------------- LSR weight folding ----------------
// Weff[hr][dm] = fold * sum_d lsr[h][d][r] * W[h*64+d][dm]   (bf16 out)
// beff[hr]    = fold * sum_d lsr[h][d][r] * bias[h*64+d]     (f32 out)
__global__ __launch_bounds__(256) void lsr_fold(const float* __restrict__ W,
                                                const float* __restrict__ bias,
                                                const float* __restrict__ lsr,
                                                float fold,
                                                u16* __restrict__ Weff,
                                                float* __restrict__ beff) {
  const int hr = blockIdx.x;                    // 0..511
  const int h = hr >> 5, r = hr & 31;
  const int tid = threadIdx.x;
  __shared__ float lw[64];
  if (tid < 64) lw[tid] = lsr[(size_t)(h * 64 + tid) * 32 + r] * fold;
  __syncthreads();
  float a0 = 0.f, a1 = 0.f, a2 = 0.f, a3 = 0.f;
  for (int d = 0; d < 64; d++) {
    float l = lw[d];
    float4 wv = *reinterpret_cast<const float4*>(W + (size_t)(h * 64 + d) * 1024 + tid * 4);
    a0 += l * wv.x; a1 += l * wv.y; a2 += l * wv.z; a3 += l * wv.w;
  }
  u16x4 o = { f2bf(a0), f2bf(a1), f2bf(a2), f2bf(a3) };
  reinterpret_cast<u16x4*>(Weff)[(size_t)hr * 256 + tid] = o;
  if (tid == 0) {
    float s = 0.f;
    for (int d = 0; d < 64; d++) s += lw[d] * bias[h * 64 + d];
    beff[hr] = s;
  }
}

// ---------------- GEMM: C[M,N] = A[M,K] * W[N,K]^T + bias, K=1024 ----------------
// 128x128 tile, BK=64, double-buffered 64KB LDS with XOR-swizzle (slot ^= row&7, T2):
// conflict-free ds_read_b128 (verified: SQ_LDS_BANK_CONFLICT = 0). Stage via
// global_load_lds with PRE-SWIZZLED global source (linear LDS dest, rule #21).
// Plain 2D grid (round-robin XCD on consecutive bm keeps A+W panels L2-resident).
template <int MODE>
__global__ __launch_bounds__(256, 2) void gemm8(const u16* __restrict__ A,
                                                const u16* __restrict__ W,
                                                const float* __restrict__ b0,
                                                const float* __restrict__ b1,
                                                const float* __restrict__ b2,
                                                void* __restrict__ Cv,
                                                u16* __restrict__ qo,
                                                u16* __restrict__ ko,
                                                int ldc) {
  __shared__ __align__(16) u16 Al[2][8192];   // [buf][128 rows][64 k] swizzled
  __shared__ __align__(16) u16 Bl[2][8192];
  const int tid  = threadIdx.x;
  const int lane = tid & 63;
  const int w    = tid >> 6;
  const int quad = lane >> 4;
  const int l16  = lane & 15;
  const int wm   = (w >> 1) << 6;
  const int wn   = (w & 1) << 6;

  const int bm = blockIdx.x << 7;
  const int bn = blockIdx.y << 7;

  const int sr = tid >> 3;
  const int sc = ((tid & 7) ^ (sr & 7)) * 8;
  const u16* Ag = A + (size_t)(bm + sr) * 1024 + sc;
  const u16* Wg = W + (size_t)(bn + sr) * 1024 + sc;

  auto stage = [&](int k0, int bsel) {        // 8 vm ops / tile
#pragma unroll
    for (int j = 0; j < 4; j++)
      async_copy16(Ag + (size_t)j * 32768 + k0, &Al[bsel][j * 2048 + w * 512]);
#pragma unroll
    for (int j = 0; j < 4; j++)
      async_copy16(Wg + (size_t)j * 32768 + k0, &Bl[bsel][j * 2048 + w * 512]);
  };

  int aoff[4], boff[4], sl[2];
#pragma unroll
  for (int mi = 0; mi < 4; mi++) aoff[mi] = (wm + mi * 16 + l16) * 64;
#pragma unroll
  for (int ni = 0; ni < 4; ni++) boff[ni] = (wn + ni * 16 + l16) * 64;
  sl[0] = ((0 + quad) ^ (l16 & 7)) * 8;
  sl[1] = ((4 + quad) ^ (l16 & 7)) * 8;

  floatx4 acc[4][4];
#pragma unroll
  for (int i = 0; i < 4; i++)
#pragma unroll
    for (int j = 0; j < 4; j++) acc[i][j] = (floatx4){0.f, 0.f, 0.f, 0.f};

  stage(0, 0);
  asm volatile("s_waitcnt vmcnt(0)" ::: "memory");
  __builtin_amdgcn_s_barrier();
  asm volatile("" ::: "memory");

  for (int i = 0; i < 16; i++) {
    if (i < 15) stage((i + 1) * 64, (i + 1) & 1);
    const u16* Ab = Al[i & 1];
    const u16* Bb = Bl[i & 1];
#pragma unroll
    for (int ks = 0; ks < 2; ks++) {
      bf16x8 af[4], bfr[4];
#pragma unroll
      for (int mi = 0; mi < 4; mi++)
        af[mi] = *reinterpret_cast<const bf16x8*>(Ab + aoff[mi] + sl[ks]);
#pragma unroll
      for (int ni = 0; ni < 4; ni++)
        bfr[ni] = *reinterpret_cast<const bf16x8*>(Bb + boff[ni] + sl[ks]);
      __builtin_amdgcn_s_setprio(1);
#pragma unroll
      for (int mi = 0; mi < 4; mi++)
#pragma unroll
        for (int ni = 0; ni < 4; ni++)
          acc[mi][ni] = MFMA16(af[mi], bfr[ni], acc[mi][ni]);
      __builtin_amdgcn_s_setprio(0);
    }
    if (i < 15) {
      asm volatile("s_waitcnt vmcnt(0)" ::: "memory");   // tile i+1 landed
      __builtin_amdgcn_s_barrier();
      asm volatile("" ::: "memory");
    }
  }

  if (MODE == 1) {
#pragma unroll
    for (int ni = 0; ni < 4; ni++) {
      int col = bn + wn + ni * 16 + l16;
      float bias = b0[col & 1023];
#pragma unroll
      for (int mi = 0; mi < 4; mi++)
#pragma unroll
        for (int r = 0; r < 4; r++) {
          int row = bm + wm + mi * 16 + quad * 4 + r;
          reinterpret_cast<float*>(Cv)[(size_t)row * ldc + col] = acc[mi][ni][r] + bias;
        }
    }
  } else {
    if (bn < 1024) {
#pragma unroll
      for (int ni = 0; ni < 4; ni++) {
        int col = bn + wn + ni * 16 + l16;
        float bias = b0[col];
#pragma unroll
        for (int mi = 0; mi < 4; mi++)
#pragma unroll
          for (int r = 0; r < 4; r++) {
            int row = bm + wm + mi * 16 + quad * 4 + r;
            reinterpret_cast<u16*>(Cv)[(size_t)row * 1024 + col] =
                f2bf(acc[mi][ni][r] + bias);
          }
      }
    } else {
      u16* outp = (bn < 1536) ? qo : ko;
      const float* bp = (bn < 1536) ? b1 : b2;
#pragma unroll
      for (int ni = 0; ni < 4; ni++) {
        int cc = (bn + wn + ni * 16 + l16) & 511;
        float bias = bp[cc];
        int hh = cc >> 5, rk = cc & 31;
#pragma unroll
        for (int mi = 0; mi < 4; mi++)
#pragma unroll
          for (int r = 0; r < 4; r++) {
            int row = bm + wm + mi * 16 + quad * 4 + r;
            size_t addr =
                ((size_t)((row >> 11) * 16 + hh) * 2048 + (row & 2047)) * 32 + rk;
            outp[addr] = f2bf(acc[mi][ni][r] + bias);
          }
      }
    }
  }
}

// ---------------- V transpose: vt[bh][d][t] ----------------
__global__ __launch_bounds__(256) void vtrans(const u16* __restrict__ V,
                                              u16* __restrict__ vt) {
  const int tb = blockIdx.x;
  const int bh = blockIdx.y;
  const int b = bh >> 4, h = bh & 15;
  __shared__ u16 Vl[64][72];
  const int tid = threadIdx.x;
#pragma unroll
  for (int it = 0; it < 2; it++) {
    int c = it * 256 + tid;
    int t = c >> 3, dc = (c & 7) * 8;
    u16x8 v = *reinterpret_cast<const u16x8*>(
        V + (size_t)(b * T_ + tb * 64 + t) * 1024 + h * 64 + dc);
    *reinterpret_cast<u16x8*>(&Vl[t][dc]) = v;
  }
  __syncthreads();
#pragma unroll
  for (int it = 0; it < 2; it++) {
    int c = it * 256 + tid;
    int d = c >> 3, tt = (c & 7) * 8;
    u16x8 o;
#pragma unroll
    for (int j = 0; j < 8; j++) o[j] = Vl[tt + j][d];
    *reinterpret_cast<u16x8*>(vt + ((size_t)bh * 64 + d) * T_ + tb * 64 + tt) = o;
  }
}

// ---------------- flash attention, key-sliced waves, register-resident P ----------------
// v3 (LDS-BW fix): wave w owns key-slice [w*16,w*16+16) of each tile for BOTH QK^T
// (all 64 q) and PV (all 64 d). Per-wave LDS reads/tile: 1 ds_read_b128 (K) +
// 4 ds_read_b64 (V, reused across 4 q-groups) vs old 4+16 -> LDS traffic /6
// (round-5 counters showed ~255 B/cyc/CU = LDS BW wall). O/rowsum become cross-wave
// partials: reduced ONCE per q-tile via conflict-free float4 LDS exchange.
// Grid (bh,p): XCD = bh%8 -> K/V L2-resident (verified FETCH 143->20MB).
__global__ __launch_bounds__(256, 4) void attn(const u16* __restrict__ qlr,
                                               const u16* __restrict__ klr,
                                               const u16* __restrict__ vt,
                                               u16* __restrict__ yatt) {
  const int bh = blockIdx.x;                      // XCD = bh%8 under round-robin
  const int b = bh >> 4, h = bh & 15;
  const int p = blockIdx.y;                       // pair index 0..15
  const int tid = threadIdx.x, lane = tid & 63, w = tid >> 6;
  const int quad = lane >> 4, l16 = lane & 15;

  __shared__ __align__(16) u16 Vt3[3][4096];      // 24 KB: V^T tiles [d=64][64 keys]
  __shared__ __align__(16) u16 Kt3[3][2048];      // 12 KB: K tiles   [64 keys][32 rk]

  const u16* qlr_bh = qlr + (size_t)bh * T_ * RK_;
  const u16* klr_bh = klr + (size_t)bh * T_ * RK_;
  const u16* vt_bh  = vt + (size_t)bh * 64 * T_;

  // V A-frag offsets for THIS wave's key slice: d = dt*16+l16, keys w*16+quad*4..+3
  int voffw[4];
#pragma unroll
  for (int dt = 0; dt < 4; dt++) {
    int d = dt * 16 + l16;
    voffw[dt] = d * 64 + (((w * 2 + (quad >> 1)) ^ (d & 7)) * 8) + (quad & 1) * 4;
  }
  // V staging source offsets (pre-swizzled so linear LDS dest ends up swizzled)
  int soffV[2];
#pragma unroll
  for (int issue = 0; issue < 2; issue++) {
    int L = issue * 256 + tid;
    int d = L >> 3, cg = L & 7;
    soffV[issue] = d * T_ + ((cg ^ (d & 7)) * 8);
  }
  // K staging: 32 pair-rows (2 keys = 128B) x 8 slots of 16B, slot s <- src slot s^(pr&7)
  const int soffK = (w * 8 + (lane >> 3)) * 64 + (((lane & 7) ^ (lane >> 3)) * 8);
  // K read for this wave's slice: key k = w*16+l16, rk slot quad
  const int koffw = (l16 >> 1) * 64 + ((((l16 & 1) * 4 + quad) ^ (l16 >> 1)) * 8) + w * 512;
  const int wub = w * 512;

  const floatx4 fzero = {0.f, 0.f, 0.f, 0.f};
  float* oxf = (float*)&Vt3[0][0];                // 6144 f32 exchange buffer
  float* rsx = (float*)&Kt3[0][0];                // 256 f32 rowsum buffer

  for (int run = 0; run < 2; run++) {
    const int qi = run ? p : 31 - p;              // heavy q-tile first
    const int q0 = qi * 64;
    if (run) __syncthreads();                     // WAR fence before restaging buf0/1

    bf16x8 qf[4];
#pragma unroll
    for (int qg = 0; qg < 4; qg++)
      qf[qg] = *reinterpret_cast<const bf16x8*>(
          qlr_bh + (size_t)(q0 + qg * 16 + l16) * 32 + quad * 8);

    auto stage = [&](int t, int bi) {             // 3 vmcnt ops per wave
      const u16* vs = vt_bh + t * 64;
      async_copy16(vs + soffV[0], &Vt3[bi][wub]);
      async_copy16(vs + soffV[1], &Vt3[bi][2048 + wub]);
      async_copy16(klr_bh + t * 2048 + soffK, &Kt3[bi][wub]);
    };

    stage(0, 0);
    if (qi >= 1) {
      stage(1, 1);
      asm volatile("s_waitcnt vmcnt(3)" ::: "memory");   // stage(0) landed
    } else {
      asm volatile("s_waitcnt vmcnt(0)" ::: "memory");
    }
    __builtin_amdgcn_s_barrier();
    asm volatile("" ::: "memory");                // no LDS reads hoist above barrier

    floatx4 oacc[4][4];                           // [dt][qg], partial over w's keys
#pragma unroll
    for (int i = 0; i < 4; i++)
#pragma unroll
      for (int j = 0; j < 4; j++) oacc[i][j] = fzero;
    float rs[4] = {0.f, 0.f, 0.f, 0.f};           // [qg]

    const u16* Vb = &Vt3[0][0];
    const u16* Kb = &Kt3[0][0];
    int cb = 0, sb = 2;

    // ---- full tiles ----
    for (int i = 0; i < qi; i++) {
      const bool do_stage = (i + 2 <= qi);
      if (do_stage) stage(i + 2, sb);

      bf16x8 kf = *reinterpret_cast<const bf16x8*>(Kb + koffw);
      uint2 pk[4];
#pragma unroll
      for (int qg = 0; qg < 4; qg++) {
        __builtin_amdgcn_s_setprio(1);
        floatx4 sv = MFMA16(kf, qf[qg], fzero);
        __builtin_amdgcn_s_setprio(0);
        float p0 = __builtin_amdgcn_exp2f(sv[0]);
        float p1 = __builtin_amdgcn_exp2f(sv[1]);
        float p2 = __builtin_amdgcn_exp2f(sv[2]);
        float p3 = __builtin_amdgcn_exp2f(sv[3]);
        rs[qg] += (p0 + p1) + (p2 + p3);
        pk[qg].x = tpack(p0, p1);
        pk[qg].y = tpack(p2, p3);
      }
      __builtin_amdgcn_s_setprio(1);
#pragma unroll
      for (int dt = 0; dt < 4; dt++) {
        s16x4 vf = *reinterpret_cast<const s16x4*>(Vb + voffw[dt]);
#pragma unroll
        for (int qg = 0; qg < 4; qg++)
          oacc[dt][qg] = MFMA1K(vf, __builtin_bit_cast(s16x4, pk[qg]), oacc[dt][qg]);
      }
      __builtin_amdgcn_s_setprio(0);

      if (do_stage) asm volatile("s_waitcnt vmcnt(3)" ::: "memory");
      else          asm volatile("s_waitcnt vmcnt(0)" ::: "memory");
      __builtin_amdgcn_s_barrier();
      asm volatile("" ::: "memory");

      cb = (cb == 2) ? 0 : cb + 1;
      Vb = &Vt3[cb][0];
      Kb = &Kt3[cb][0];
      if (do_stage) sb = (sb == 2) ? 0 : sb + 1;
    }

    // ---- diagonal tile (masked): key_local = w*16+quad*4+r, q_local = qg*16+l16 ----
    {
      bf16x8 kf = *reinterpret_cast<const bf16x8*>(Kb + koffw);
      const int keyl = w * 16 + quad * 4;
      uint2 pk[4];
#pragma unroll
      for (int qg = 0; qg < 4; qg++) {
        floatx4 sv = MFMA16(kf, qf[qg], fzero);
        const int thr = qg * 16 + l16;
        float pr[4];
#pragma unroll
        for (int r = 0; r < 4; r++) {
          float e = __builtin_amdgcn_exp2f(sv[r]);
          pr[r] = (keyl + r <= thr) ? e : 0.f;
        }
        rs[qg] += (pr[0] + pr[1]) + (pr[2] + pr[3]);
        pk[qg].x = tpack(pr[0], pr[1]);
        pk[qg].y = tpack(pr[2], pr[3]);
      }
      __builtin_amdgcn_s_setprio(1);
#pragma unroll
      for (int dt = 0; dt < 4; dt++) {
        s16x4 vf = *reinterpret_cast<const s16x4*>(Vb + voffw[dt]);
#pragma unroll
        for (int qg = 0; qg < 4; qg++)
          oacc[dt][qg] = MFMA1K(vf, __builtin_bit_cast(s16x4, pk[qg]), oacc[dt][qg]);
      }
      __builtin_amdgcn_s_setprio(0);
    }

    // wave-local rowsum over quads: all lanes end with wave total for (qg, l16)
#pragma unroll
    for (int qg = 0; qg < 4; qg++) {
      rs[qg] += __shfl_xor(rs[qg], 16);
      rs[qg] += __shfl_xor(rs[qg], 32);
    }

    // ---- cross-wave reduction (once per q-tile) ----
    // oxf layout: [dtl&1][ws][qg][lane] float4 -> (dtl&1)*3072 + ws*1024 + qg*256 + lane*4
    __syncthreads();                              // tiles free; exchange begins
    floatx4 ofin[4];                              // final O for dt == w, [qg]
    float inv[4];
    // phase A: dtl 0,1 writes + rowsums
#pragma unroll
    for (int dtl = 0; dtl < 2; dtl++) {
      if (w != dtl) {
        int ws = w - (w > dtl ? 1 : 0);
#pragma unroll
        for (int qg = 0; qg < 4; qg++)
          *reinterpret_cast<floatx4*>(&oxf[dtl * 3072 + ws * 1024 + qg * 256 + lane * 4]) =
              oacc[dtl][qg];
      }
    }
    if (quad == 0) {
#pragma unroll
      for (int qg = 0; qg < 4; qg++) rsx[(qg * 16 + l16) * 4 + w] = rs[qg];
    }
    __syncthreads();
#pragma unroll
    for (int dtl = 0; dtl < 2; dtl++) {
      if (w == dtl) {
#pragma unroll
        for (int qg = 0; qg < 4; qg++) {
          floatx4 s = oacc[dtl][qg];
#pragma unroll
          for (int ws = 0; ws < 3; ws++)
            s += *reinterpret_cast<const floatx4*>(
                &oxf[dtl * 3072 + ws * 1024 + qg * 256 + lane * 4]);
          ofin[qg] = s;
        }
      }
    }
#pragma unroll
    for (int qg = 0; qg < 4; qg++) {
      float4 rv = *reinterpret_cast<const float4*>(&rsx[(qg * 16 + l16) * 4]);
      inv[qg] = 1.f / ((rv.x + rv.y) + (rv.z + rv.w));
    }
    __syncthreads();                              // phase A reads done
    // phase B: dtl 2,3
#pragma unroll
    for (int dtl = 2; dtl < 4; dtl++) {
      if (w != dtl) {
        int ws = w - (w > dtl ? 1 : 0);
#pragma unroll
        for (int qg = 0; qg < 4; qg++)
          *reinterpret_cast<floatx4*>(&oxf[(dtl & 1) * 3072 + ws * 1024 + qg * 256 + lane * 4]) =
              oacc[dtl][qg];
      }
    }
    __syncthreads();
#pragma unroll
    for (int dtl = 2; dtl < 4; dtl++) {
      if (w == dtl) {
#pragma unroll
        for (int qg = 0; qg < 4; qg++) {
          floatx4 s = oacc[dtl][qg];
#pragma unroll
          for (int ws = 0; ws < 3; ws++)
            s += *reinterpret_cast<const floatx4*>(
                &oxf[(dtl & 1) * 3072 + ws * 1024 + qg * 256 + lane * 4]);
          ofin[qg] = s;
        }
      }
    }

    // store: wave w owns d = w*16 + quad*4 + r, q = q0 + qg*16 + l16
#pragma unroll
    for (int qg = 0; qg < 4; qg++) {
      int q = q0 + qg * 16 + l16;
      uint2 ov = { pack_bf(ofin[qg][0] * inv[qg], ofin[qg][1] * inv[qg]),
                   pack_bf(ofin[qg][2] * inv[qg], ofin[qg][3] * inv[qg]) };
      *reinterpret_cast<uint2*>(
          yatt + (size_t)(b * T_ + q) * 1024 + h * 64 + w * 16 + quad * 4) = ov;
    }
  }
}

// ---------------- launch ----------------
extern "C" void kernel_launch(void* const* d_in, const int* in_sizes, int n_in,
                              void* d_out, int out_size, void* d_ws, size_t ws_size,
                              hipStream_t stream) {
  const float* x   = (const float*)d_in[0];
  const float* Wq  = (const float*)d_in[1];
  const float* bq  = (const float*)d_in[2];
  const float* Wk  = (const float*)d_in[3];
  const float* bk  = (const float*)d_in[4];
  const float* Wv  = (const float*)d_in[5];
  const float* bv  = (const float*)d_in[6];
  const float* Wo  = (const float*)d_in[7];
  const float* bo  = (const float*)d_in[8];
  const float* Wql = (const float*)d_in[9];
  const float* Wkl = (const float*)d_in[10];
  float* out = (float*)d_out;

  char* ws = (char*)d_ws;
  u16*   xb    = (u16*)(ws);                  // 8192x1024 bf16 (16 MB) -- reused as vt
  u16*   Wcat  = (u16*)(ws + 16777216);       // 3072x1024 bf16 (6 MB): Wv | Weffq | Weffk | Wo
  float* beffq = (float*)(ws + 23068672);     // 512 f32
  float* beffk = (float*)(ws + 23072768);     // 512 f32
  u16*   Vbuf  = (u16*)(ws + 25165824);       // 8192x1024 bf16 (16 MB)
  u16*   qlr   = (u16*)(ws + 41943040);       // 64x2048x32 bf16 (8 MB)
  u16*   klr   = (u16*)(ws + 50331648);       // 64x2048x32 bf16 (8 MB)
  u16*   yatt  = (u16*)(ws + 58720256);       // 8192x1024 bf16 (16 MB)
  u16*   vt    = xb;                          // [bh][64][2048] bf16, after gemm0

  const float foldq = 0.25506100790944405f;   // (1/sqrt(32))*log2(e)

  cvt_x<<<dim3(8192), 256, 0, stream>>>(x, xb, 2097152);
  cvt_wvo<<<dim3(2048), 256, 0, stream>>>(Wv, Wo, Wcat);
  lsr_fold<<<dim3(512), 256, 0, stream>>>(Wq, bq, Wql, foldq, Wcat + 1048576, beffq);
  lsr_fold<<<dim3(512), 256, 0, stream>>>(Wk, bk, Wkl, 1.0f, Wcat + 1572864, beffk);
  gemm8<2><<<dim3(64, 16), 256, 0, stream>>>(xb, Wcat, bv, beffq, beffk,
                                             Vbuf, qlr, klr, 0);
  vtrans<<<dim3(32, 64), 256, 0, stream>>>(Vbuf, vt);
  attn<<<dim3(64, 16), 256, 0, stream>>>(qlr, klr, vt, yatt);
  gemm8<1><<<dim3(64, 8), 256, 0, stream>>>(yatt, Wcat + 2097152, bo, bo, bo,
                                            out, nullptr, nullptr, 1024);
}

// Round 7
// 242.932 us; speedup vs baseline: 1.0645x; 1.0645x over previous
//
#include <hip/hip_runtime.h>

#define B_  4
#define T_  2048
#define H_  16
#define DM_ 1024
#define DH_ 64
#define RK_ 32

using u16 = unsigned short;
using u32 = unsigned int;
typedef float  floatx4 __attribute__((ext_vector_type(4)));
typedef __bf16 bf16x8  __attribute__((ext_vector_type(8)));
typedef u16    u16x8   __attribute__((ext_vector_type(8)));
typedef u16    u16x4   __attribute__((ext_vector_type(4)));
typedef short  s16x4   __attribute__((ext_vector_type(4)));

#define MFMA16(a,b,c) __builtin_amdgcn_mfma_f32_16x16x32_bf16((a),(b),(c),0,0,0)
// K=16 bf16 MFMA: A/B frag = 4 bf16 (k = quad*4+j), C/D same 16x16 layout
#define MFMA1K(a,b,c) __builtin_amdgcn_mfma_f32_16x16x16bf16_1k((a),(b),(c),0,0,0)

__device__ __forceinline__ u16 f2bf(float f) {
  unsigned u = __float_as_uint(f);
  u += 0x7fffu + ((u >> 16) & 1u);   // RNE
  return (u16)(u >> 16);
}
// RNE pack: (bf16(b)<<16)|bf16(a)
__device__ __forceinline__ u32 pack_bf(float a, float b) {
  u32 ua = __float_as_uint(a); ua += 0x7fffu + ((ua >> 16) & 1u);
  u32 ub = __float_as_uint(b); ub += 0x7fffu + ((ub >> 16) & 1u);
  return __builtin_amdgcn_perm(ub, ua, 0x07060302u);
}
// truncation pack (1 instr) — for P in the hot loop (values > 0)
__device__ __forceinline__ u32 tpack(float a, float b) {
  return __builtin_amdgcn_perm(__float_as_uint(b), __float_as_uint(a), 0x07060302u);
}

// async global->LDS, 16B per lane. LDS dest is wave-uniform base; HW adds lane*16.
__device__ __forceinline__ void async_copy16(const u16* g, const u16* lds_uniform_base) {
  __builtin_amdgcn_global_load_lds(
      (const __attribute__((address_space(1))) unsigned int*)(unsigned long long)g,
      (__attribute__((address_space(3))) unsigned int*)(unsigned int)(unsigned long long)lds_uniform_base,
      16, 0, 0);
}

// ---------------- conversion kernels ----------------
__global__ __launch_bounds__(256) void cvt_x(const float* __restrict__ s,
                                             u16* __restrict__ d, int n4) {
  int i = blockIdx.x * 256 + threadIdx.x;
  if (i >= n4) return;
  float4 v = reinterpret_cast<const float4*>(s)[i];
  u16x4 o = { f2bf(v.x), f2bf(v.y), f2bf(v.z), f2bf(v.w) };
  reinterpret_cast<u16x4*>(d)[i] = o;
}

// Wv -> Wcat rows [0,1024); Wo -> Wcat rows [2048,3072)
__global__ __launch_bounds__(256) void cvt_wvo(const float* __restrict__ Wv,
                                               const float* __restrict__ Wo,
                                               u16* __restrict__ Wcat) {
  int i = blockIdx.x * 256 + threadIdx.x;       // 2 x 262144 float4-groups
  int reg = i >> 18;
  const float* s = reg ? Wo : Wv;
  int j = i & 262143;
  float4 v = reinterpret_cast<const float4*>(s)[j];
  u16x4 o = { f2bf(v.x), f2bf(v.y), f2bf(v.z), f2bf(v.w) };
  reinterpret_cast<u16x4*>(Wcat)[(reg ? 524288 : 0) + j] = o;
}

// ---------------- LSR weight folding ----------------
// Weff[hr][dm] = fold * sum_d lsr[h][d][r] * W[h*64+d][dm]   (bf16 out)
// beff[hr]    = fold * sum_d lsr[h][d][r] * bias[h*64+d]     (f32 out)
__global__ __launch_bounds__(256) void lsr_fold(const float* __restrict__ W,
                                                const float* __restrict__ bias,
                                                const float* __restrict__ lsr,
                                                float fold,
                                                u16* __restrict__ Weff,
                                                float* __restrict__ beff) {
  const int hr = blockIdx.x;                    // 0..511
  const int h = hr >> 5, r = hr & 31;
  const int tid = threadIdx.x;
  __shared__ float lw[64];
  if (tid < 64) lw[tid] = lsr[(size_t)(h * 64 + tid) * 32 + r] * fold;
  __syncthreads();
  float a0 = 0.f, a1 = 0.f, a2 = 0.f, a3 = 0.f;
  for (int d = 0; d < 64; d++) {
    float l = lw[d];
    float4 wv = *reinterpret_cast<const float4*>(W + (size_t)(h * 64 + d) * 1024 + tid * 4);
    a0 += l * wv.x; a1 += l * wv.y; a2 += l * wv.z; a3 += l * wv.w;
  }
  u16x4 o = { f2bf(a0), f2bf(a1), f2bf(a2), f2bf(a3) };
  reinterpret_cast<u16x4*>(Weff)[(size_t)hr * 256 + tid] = o;
  if (tid == 0) {
    float s = 0.f;
    for (int d = 0; d < 64; d++) s += lw[d] * bias[h * 64 + d];
    beff[hr] = s;
  }
}

// ---------------- GEMM: C[M,N] = A[M,K] * W[N,K]^T + bias, K=1024 ----------------
// 128x128 tile, BK=64, double-buffered 64KB LDS with XOR-swizzle (slot ^= row&7, T2):
// conflict-free ds_read_b128 (verified: SQ_LDS_BANK_CONFLICT = 0). Stage via
// global_load_lds with PRE-SWIZZLED global source (linear LDS dest, rule #21).
// Plain 2D grid (round-robin XCD on consecutive bm keeps A+W panels L2-resident).
template <int MODE>
__global__ __launch_bounds__(256, 2) void gemm8(const u16* __restrict__ A,
                                                const u16* __restrict__ W,
                                                const float* __restrict__ b0,
                                                const float* __restrict__ b1,
                                                const float* __restrict__ b2,
                                                void* __restrict__ Cv,
                                                u16* __restrict__ qo,
                                                u16* __restrict__ ko,
                                                int ldc) {
  __shared__ __align__(16) u16 Al[2][8192];   // [buf][128 rows][64 k] swizzled
  __shared__ __align__(16) u16 Bl[2][8192];
  const int tid  = threadIdx.x;
  const int lane = tid & 63;
  const int w    = tid >> 6;
  const int quad = lane >> 4;
  const int l16  = lane & 15;
  const int wm   = (w >> 1) << 6;
  const int wn   = (w & 1) << 6;

  const int bm = blockIdx.x << 7;
  const int bn = blockIdx.y << 7;

  const int sr = tid >> 3;
  const int sc = ((tid & 7) ^ (sr & 7)) * 8;
  const u16* Ag = A + (size_t)(bm + sr) * 1024 + sc;
  const u16* Wg = W + (size_t)(bn + sr) * 1024 + sc;

  auto stage = [&](int k0, int bsel) {        // 8 vm ops / tile
#pragma unroll
    for (int j = 0; j < 4; j++)
      async_copy16(Ag + (size_t)j * 32768 + k0, &Al[bsel][j * 2048 + w * 512]);
#pragma unroll
    for (int j = 0; j < 4; j++)
      async_copy16(Wg + (size_t)j * 32768 + k0, &Bl[bsel][j * 2048 + w * 512]);
  };

  int aoff[4], boff[4], sl[2];
#pragma unroll
  for (int mi = 0; mi < 4; mi++) aoff[mi] = (wm + mi * 16 + l16) * 64;
#pragma unroll
  for (int ni = 0; ni < 4; ni++) boff[ni] = (wn + ni * 16 + l16) * 64;
  sl[0] = ((0 + quad) ^ (l16 & 7)) * 8;
  sl[1] = ((4 + quad) ^ (l16 & 7)) * 8;

  floatx4 acc[4][4];
#pragma unroll
  for (int i = 0; i < 4; i++)
#pragma unroll
    for (int j = 0; j < 4; j++) acc[i][j] = (floatx4){0.f, 0.f, 0.f, 0.f};

  stage(0, 0);
  asm volatile("s_waitcnt vmcnt(0)" ::: "memory");
  __builtin_amdgcn_s_barrier();
  asm volatile("" ::: "memory");

  for (int i = 0; i < 16; i++) {
    if (i < 15) stage((i + 1) * 64, (i + 1) & 1);
    const u16* Ab = Al[i & 1];
    const u16* Bb = Bl[i & 1];
#pragma unroll
    for (int ks = 0; ks < 2; ks++) {
      bf16x8 af[4], bfr[4];
#pragma unroll
      for (int mi = 0; mi < 4; mi++)
        af[mi] = *reinterpret_cast<const bf16x8*>(Ab + aoff[mi] + sl[ks]);
#pragma unroll
      for (int ni = 0; ni < 4; ni++)
        bfr[ni] = *reinterpret_cast<const bf16x8*>(Bb + boff[ni] + sl[ks]);
      __builtin_amdgcn_s_setprio(1);
#pragma unroll
      for (int mi = 0; mi < 4; mi++)
#pragma unroll
        for (int ni = 0; ni < 4; ni++)
          acc[mi][ni] = MFMA16(af[mi], bfr[ni], acc[mi][ni]);
      __builtin_amdgcn_s_setprio(0);
    }
    if (i < 15) {
      asm volatile("s_waitcnt vmcnt(0)" ::: "memory");   // tile i+1 landed
      __builtin_amdgcn_s_barrier();
      asm volatile("" ::: "memory");
    }
  }

  if (MODE == 1) {
#pragma unroll
    for (int ni = 0; ni < 4; ni++) {
      int col = bn + wn + ni * 16 + l16;
      float bias = b0[col & 1023];
#pragma unroll
      for (int mi = 0; mi < 4; mi++)
#pragma unroll
        for (int r = 0; r < 4; r++) {
          int row = bm + wm + mi * 16 + quad * 4 + r;
          reinterpret_cast<float*>(Cv)[(size_t)row * ldc + col] = acc[mi][ni][r] + bias;
        }
    }
  } else {
    if (bn < 1024) {
#pragma unroll
      for (int ni = 0; ni < 4; ni++) {
        int col = bn + wn + ni * 16 + l16;
        float bias = b0[col];
#pragma unroll
        for (int mi = 0; mi < 4; mi++)
#pragma unroll
          for (int r = 0; r < 4; r++) {
            int row = bm + wm + mi * 16 + quad * 4 + r;
            reinterpret_cast<u16*>(Cv)[(size_t)row * 1024 + col] =
                f2bf(acc[mi][ni][r] + bias);
          }
      }
    } else {
      u16* outp = (bn < 1536) ? qo : ko;
      const float* bp = (bn < 1536) ? b1 : b2;
#pragma unroll
      for (int ni = 0; ni < 4; ni++) {
        int cc = (bn + wn + ni * 16 + l16) & 511;
        float bias = bp[cc];
        int hh = cc >> 5, rk = cc & 31;
#pragma unroll
        for (int mi = 0; mi < 4; mi++)
#pragma unroll
          for (int r = 0; r < 4; r++) {
            int row = bm + wm + mi * 16 + quad * 4 + r;
            size_t addr =
                ((size_t)((row >> 11) * 16 + hh) * 2048 + (row & 2047)) * 32 + rk;
            outp[addr] = f2bf(acc[mi][ni][r] + bias);
          }
      }
    }
  }
}

// ---------------- V transpose: vt[bh][d][t] ----------------
__global__ __launch_bounds__(256) void vtrans(const u16* __restrict__ V,
                                              u16* __restrict__ vt) {
  const int tb = blockIdx.x;
  const int bh = blockIdx.y;
  const int b = bh >> 4, h = bh & 15;
  __shared__ u16 Vl[64][72];
  const int tid = threadIdx.x;
#pragma unroll
  for (int it = 0; it < 2; it++) {
    int c = it * 256 + tid;
    int t = c >> 3, dc = (c & 7) * 8;
    u16x8 v = *reinterpret_cast<const u16x8*>(
        V + (size_t)(b * T_ + tb * 64 + t) * 1024 + h * 64 + dc);
    *reinterpret_cast<u16x8*>(&Vl[t][dc]) = v;
  }
  __syncthreads();
#pragma unroll
  for (int it = 0; it < 2; it++) {
    int c = it * 256 + tid;
    int d = c >> 3, tt = (c & 7) * 8;
    u16x8 o;
#pragma unroll
    for (int j = 0; j < 8; j++) o[j] = Vl[tt + j][d];
    *reinterpret_cast<u16x8*>(vt + ((size_t)bh * 64 + d) * T_ + tb * 64 + tt) = o;
  }
}

// ---------------- flash attention, QBLK=128, register-resident P ----------------
// v4: round-5 structure (wave owns q rows, full K/V tile reads) but each wave now
// serves TWO q-groups (q = q0 + qg*64 + w*16 + l16): the same kf[4] + 16 V-frag
// LDS reads feed 2x the MFMA work -> per-work LDS traffic and bank conflicts
// halve (round-5 was at the ~256B/cyc LDS wall; round-6's key-slice fix spilled
// to scratch - avoided here: oacc[4][2]=32f32, ~110 VGPR, bounds(256,2)).
// Pairing (15-p, p) over 128-row q-tiles: uniform 34 key-tiles/block, 512 blocks
// = 2/CU. Grid (bh,p): XCD = bh%8 -> K/V L2-resident (FETCH ~20MB verified).
// Causal tail = two masked tiles: tileA (qg0 masked, qg1 full), tileB (qg1 masked).
__global__ __launch_bounds__(256, 2) void attn(const u16* __restrict__ qlr,
                                               const u16* __restrict__ klr,
                                               const u16* __restrict__ vt,
                                               u16* __restrict__ yatt) {
  const int bh = blockIdx.x;                      // XCD = bh%8 under round-robin
  const int b = bh >> 4, h = bh & 15;
  const int p = blockIdx.y;                       // pair index 0..7
  const int tid = threadIdx.x, lane = tid & 63, w = tid >> 6;
  const int quad = lane >> 4, l16 = lane & 15;

  __shared__ __align__(16) u16 Vt3[3][4096];      // 24 KB: V^T tiles [d=64][64 keys]
  __shared__ __align__(16) u16 Kt3[3][2048];      // 12 KB: K tiles   [64 keys][32 rk]

  const u16* qlr_bh = qlr + (size_t)bh * T_ * RK_;
  const u16* klr_bh = klr + (size_t)bh * T_ * RK_;
  const u16* vt_bh  = vt + (size_t)bh * 64 * T_;

  // V LDS read offsets: A-frag (nt,dt): d=dt*16+l16, keys nt*16+quad*4..+3
  int voff[4][4];
#pragma unroll
  for (int nt = 0; nt < 4; nt++)
#pragma unroll
    for (int dt = 0; dt < 4; dt++) {
      int d = dt * 16 + l16;
      voff[nt][dt] = d * 64 + (((nt * 2 + (quad >> 1)) ^ (d & 7)) * 8) + (quad & 1) * 4;
    }
  // V staging source offsets (pre-swizzled so linear LDS dest ends up swizzled)
  int soffV[2];
#pragma unroll
  for (int issue = 0; issue < 2; issue++) {
    int L = issue * 256 + tid;
    int d = L >> 3, cg = L & 7;
    soffV[issue] = d * T_ + ((cg ^ (d & 7)) * 8);
  }
  // K staging: 32 pair-rows (2 keys = 128B) x 8 slots of 16B, slot s <- src slot s^(pr&7)
  const int soffK = (w * 8 + (lane >> 3)) * 64 + (((lane & 7) ^ (lane >> 3)) * 8);
  // K read: key k=nt*16+l16, rk slot quad -> koff + nt*512
  const int koff = (l16 >> 1) * 64 + ((((l16 & 1) * 4 + quad) ^ (l16 >> 1)) * 8);
  const int wub = w * 512;

  const floatx4 fzero = {0.f, 0.f, 0.f, 0.f};
  const int thrq = w * 16 + l16;                  // local-64 q index owned by lane

  for (int run = 0; run < 2; run++) {
    const int j = run ? p : 15 - p;               // heavy q-tile first
    const int q0 = j << 7;
    const int nfull = 2 * j;                      // key-tiles fully below the q-tile
    if (run) __syncthreads();                     // WAR fence before restaging buf0/1

    bf16x8 qf[2];
#pragma unroll
    for (int qg = 0; qg < 2; qg++)
      qf[qg] = *reinterpret_cast<const bf16x8*>(
          qlr_bh + (size_t)(q0 + qg * 64 + thrq) * 32 + quad * 8);

    auto stage = [&](int t, int bi) {             // 3 vmcnt ops per wave
      const u16* vs = vt_bh + t * 64;
      async_copy16(vs + soffV[0], &Vt3[bi][wub]);
      async_copy16(vs + soffV[1], &Vt3[bi][2048 + wub]);
      async_copy16(klr_bh + t * 2048 + soffK, &Kt3[bi][wub]);
    };

    stage(0, 0);
    stage(1, 1);                                  // nkt = nfull+2 >= 2 always
    asm volatile("s_waitcnt vmcnt(3)" ::: "memory");   // stage(0) landed
    __builtin_amdgcn_s_barrier();
    asm volatile("" ::: "memory");                // no LDS reads hoist above barrier

    floatx4 oacc[4][2];                           // [dt][qg]
#pragma unroll
    for (int i = 0; i < 4; i++)
#pragma unroll
      for (int jg = 0; jg < 2; jg++) oacc[i][jg] = fzero;
    float rs[2] = {0.f, 0.f};

    const u16* Vb = &Vt3[0][0];
    const u16* Kb = &Kt3[0][0];
    int cb = 0, sb = 2;

    // ---- full tiles ----
    for (int i = 0; i < nfull; i++) {
      stage(i + 2, sb);                           // i+2 <= nfull+1 = last tile, always valid

      bf16x8 kf[4];
#pragma unroll
      for (int nt = 0; nt < 4; nt++)
        kf[nt] = *reinterpret_cast<const bf16x8*>(Kb + koff + nt * 512);

      uint2 pk[4][2];
#pragma unroll
      for (int qg = 0; qg < 2; qg++) {
        __builtin_amdgcn_s_setprio(1);
        floatx4 sv[4];
#pragma unroll
        for (int nt = 0; nt < 4; nt++) sv[nt] = MFMA16(kf[nt], qf[qg], fzero);
        __builtin_amdgcn_s_setprio(0);
#pragma unroll
        for (int nt = 0; nt < 4; nt++) {
          float p0 = __builtin_amdgcn_exp2f(sv[nt][0]);
          float p1 = __builtin_amdgcn_exp2f(sv[nt][1]);
          float p2 = __builtin_amdgcn_exp2f(sv[nt][2]);
          float p3 = __builtin_amdgcn_exp2f(sv[nt][3]);
          rs[qg] += (p0 + p1) + (p2 + p3);
          pk[nt][qg].x = tpack(p0, p1);
          pk[nt][qg].y = tpack(p2, p3);
        }
      }
      __builtin_amdgcn_s_setprio(1);
#pragma unroll
      for (int dt = 0; dt < 4; dt++)
#pragma unroll
        for (int nt = 0; nt < 4; nt++) {
          s16x4 vf = *reinterpret_cast<const s16x4*>(Vb + voff[nt][dt]);
          oacc[dt][0] = MFMA1K(vf, __builtin_bit_cast(s16x4, pk[nt][0]), oacc[dt][0]);
          oacc[dt][1] = MFMA1K(vf, __builtin_bit_cast(s16x4, pk[nt][1]), oacc[dt][1]);
        }
      __builtin_amdgcn_s_setprio(0);

      asm volatile("s_waitcnt vmcnt(3)" ::: "memory");  // stage(i+1) done
      __builtin_amdgcn_s_barrier();
      asm volatile("" ::: "memory");

      cb = (cb == 2) ? 0 : cb + 1;
      Vb = &Vt3[cb][0];
      Kb = &Kt3[cb][0];
      sb = (sb == 2) ? 0 : sb + 1;
    }

    // ---- masked tile A (keys 2j*64..+63): qg0 masked (kl <= thrq), qg1 full ----
    {
      bf16x8 kf[4];
#pragma unroll
      for (int nt = 0; nt < 4; nt++)
        kf[nt] = *reinterpret_cast<const bf16x8*>(Kb + koff + nt * 512);

      uint2 pk[4][2];
#pragma unroll
      for (int nt = 0; nt < 4; nt++) {
        floatx4 sv = MFMA16(kf[nt], qf[0], fzero);
        const int keyl = nt * 16 + quad * 4;
        float pr[4];
#pragma unroll
        for (int r = 0; r < 4; r++) {
          float e = __builtin_amdgcn_exp2f(sv[r]);
          pr[r] = (keyl + r <= thrq) ? e : 0.f;
        }
        rs[0] += (pr[0] + pr[1]) + (pr[2] + pr[3]);
        pk[nt][0].x = tpack(pr[0], pr[1]);
        pk[nt][0].y = tpack(pr[2], pr[3]);
      }
#pragma unroll
      for (int nt = 0; nt < 4; nt++) {
        floatx4 sv = MFMA16(kf[nt], qf[1], fzero);
        float p0 = __builtin_amdgcn_exp2f(sv[0]);
        float p1 = __builtin_amdgcn_exp2f(sv[1]);
        float p2 = __builtin_amdgcn_exp2f(sv[2]);
        float p3 = __builtin_amdgcn_exp2f(sv[3]);
        rs[1] += (p0 + p1) + (p2 + p3);
        pk[nt][1].x = tpack(p0, p1);
        pk[nt][1].y = tpack(p2, p3);
      }
      __builtin_amdgcn_s_setprio(1);
#pragma unroll
      for (int dt = 0; dt < 4; dt++)
#pragma unroll
        for (int nt = 0; nt < 4; nt++) {
          s16x4 vf = *reinterpret_cast<const s16x4*>(Vb + voff[nt][dt]);
          oacc[dt][0] = MFMA1K(vf, __builtin_bit_cast(s16x4, pk[nt][0]), oacc[dt][0]);
          oacc[dt][1] = MFMA1K(vf, __builtin_bit_cast(s16x4, pk[nt][1]), oacc[dt][1]);
        }
      __builtin_amdgcn_s_setprio(0);

      asm volatile("s_waitcnt vmcnt(0)" ::: "memory");  // last tile landed
      __builtin_amdgcn_s_barrier();
      asm volatile("" ::: "memory");

      cb = (cb == 2) ? 0 : cb + 1;
      Vb = &Vt3[cb][0];
      Kb = &Kt3[cb][0];
    }

    // ---- masked tile B (keys (2j+1)*64..+63): qg0 all-masked (skip), qg1 masked ----
    {
      bf16x8 kf[4];
#pragma unroll
      for (int nt = 0; nt < 4; nt++)
        kf[nt] = *reinterpret_cast<const bf16x8*>(Kb + koff + nt * 512);

      uint2 pk[4];
#pragma unroll
      for (int nt = 0; nt < 4; nt++) {
        floatx4 sv = MFMA16(kf[nt], qf[1], fzero);
        const int keyl = nt * 16 + quad * 4;
        float pr[4];
#pragma unroll
        for (int r = 0; r < 4; r++) {
          float e = __builtin_amdgcn_exp2f(sv[r]);
          pr[r] = (keyl + r <= thrq) ? e : 0.f;
        }
        rs[1] += (pr[0] + pr[1]) + (pr[2] + pr[3]);
        pk[nt].x = tpack(pr[0], pr[1]);
        pk[nt].y = tpack(pr[2], pr[3]);
      }
      __builtin_amdgcn_s_setprio(1);
#pragma unroll
      for (int dt = 0; dt < 4; dt++)
#pragma unroll
        for (int nt = 0; nt < 4; nt++) {
          s16x4 vf = *reinterpret_cast<const s16x4*>(Vb + voff[nt][dt]);
          oacc[dt][1] = MFMA1K(vf, __builtin_bit_cast(s16x4, pk[nt]), oacc[dt][1]);
        }
      __builtin_amdgcn_s_setprio(0);
    }

    // row-sum across the 4 quads; normalize; store O^T (d = dt*16+quad*4+r)
#pragma unroll
    for (int qg = 0; qg < 2; qg++) {
      rs[qg] += __shfl_xor(rs[qg], 16);
      rs[qg] += __shfl_xor(rs[qg], 32);
    }
#pragma unroll
    for (int qg = 0; qg < 2; qg++) {
      float inv = 1.f / rs[qg];
      const int qrow = q0 + qg * 64 + thrq;
#pragma unroll
      for (int dt = 0; dt < 4; dt++) {
        uint2 ov = { pack_bf(oacc[dt][qg][0] * inv, oacc[dt][qg][1] * inv),
                     pack_bf(oacc[dt][qg][2] * inv, oacc[dt][qg][3] * inv) };
        *reinterpret_cast<uint2*>(
            yatt + (size_t)(b * T_ + qrow) * 1024 + h * 64 + dt * 16 + quad * 4) = ov;
      }
    }
  }
}

// ---------------- launch ----------------
extern "C" void kernel_launch(void* const* d_in, const int* in_sizes, int n_in,
                              void* d_out, int out_size, void* d_ws, size_t ws_size,
                              hipStream_t stream) {
  const float* x   = (const float*)d_in[0];
  const float* Wq  = (const float*)d_in[1];
  const float* bq  = (const float*)d_in[2];
  const float* Wk  = (const float*)d_in[3];
  const float* bk  = (const float*)d_in[4];
  const float* Wv  = (const float*)d_in[5];
  const float* bv  = (const float*)d_in[6];
  const float* Wo  = (const float*)d_in[7];
  const float* bo  = (const float*)d_in[8];
  const float* Wql = (const float*)d_in[9];
  const float* Wkl = (const float*)d_in[10];
  float* out = (float*)d_out;

  char* ws = (char*)d_ws;
  u16*   xb    = (u16*)(ws);                  // 8192x1024 bf16 (16 MB) -- reused as vt
  u16*   Wcat  = (u16*)(ws + 16777216);       // 3072x1024 bf16 (6 MB): Wv | Weffq | Weffk | Wo
  float* beffq = (float*)(ws + 23068672);     // 512 f32
  float* beffk = (float*)(ws + 23072768);     // 512 f32
  u16*   Vbuf  = (u16*)(ws + 25165824);       // 8192x1024 bf16 (16 MB)
  u16*   qlr   = (u16*)(ws + 41943040);       // 64x2048x32 bf16 (8 MB)
  u16*   klr   = (u16*)(ws + 50331648);       // 64x2048x32 bf16 (8 MB)
  u16*   yatt  = (u16*)(ws + 58720256);       // 8192x1024 bf16 (16 MB)
  u16*   vt    = xb;                          // [bh][64][2048] bf16, after gemm0

  const float foldq = 0.25506100790944405f;   // (1/sqrt(32))*log2(e)

  cvt_x<<<dim3(8192), 256, 0, stream>>>(x, xb, 2097152);
  cvt_wvo<<<dim3(2048), 256, 0, stream>>>(Wv, Wo, Wcat);
  lsr_fold<<<dim3(512), 256, 0, stream>>>(Wq, bq, Wql, foldq, Wcat + 1048576, beffq);
  lsr_fold<<<dim3(512), 256, 0, stream>>>(Wk, bk, Wkl, 1.0f, Wcat + 1572864, beffk);
  gemm8<2><<<dim3(64, 16), 256, 0, stream>>>(xb, Wcat, bv, beffq, beffk,
                                             Vbuf, qlr, klr, 0);
  vtrans<<<dim3(32, 64), 256, 0, stream>>>(Vbuf, vt);
  attn<<<dim3(64, 8), 256, 0, stream>>>(qlr, klr, vt, yatt);
  gemm8<1><<<dim3(64, 8), 256, 0, stream>>>(yatt, Wcat + 2097152, bo, bo, bo,
                                            out, nullptr, nullptr, 1024);
}

// Round 8
// 234.514 us; speedup vs baseline: 1.1027x; 1.0359x over previous
//
#include <hip/hip_runtime.h>

#define B_  4
#define T_  2048
#define H_  16
#define DM_ 1024
#define DH_ 64
#define RK_ 32

using u16 = unsigned short;
using u32 = unsigned int;
typedef float  floatx4 __attribute__((ext_vector_type(4)));
typedef __bf16 bf16x8  __attribute__((ext_vector_type(8)));
typedef u16    u16x8   __attribute__((ext_vector_type(8)));
typedef u16    u16x4   __attribute__((ext_vector_type(4)));
typedef short  s16x4   __attribute__((ext_vector_type(4)));

#define MFMA16(a,b,c) __builtin_amdgcn_mfma_f32_16x16x32_bf16((a),(b),(c),0,0,0)
// K=16 bf16 MFMA: A/B frag = 4 bf16 (k = quad*4+j), C/D same 16x16 layout
#define MFMA1K(a,b,c) __builtin_amdgcn_mfma_f32_16x16x16bf16_1k((a),(b),(c),0,0,0)

__device__ __forceinline__ u16 f2bf(float f) {
  unsigned u = __float_as_uint(f);
  u += 0x7fffu + ((u >> 16) & 1u);   // RNE
  return (u16)(u >> 16);
}
// RNE pack: (bf16(b)<<16)|bf16(a)
__device__ __forceinline__ u32 pack_bf(float a, float b) {
  u32 ua = __float_as_uint(a); ua += 0x7fffu + ((ua >> 16) & 1u);
  u32 ub = __float_as_uint(b); ub += 0x7fffu + ((ub >> 16) & 1u);
  return __builtin_amdgcn_perm(ub, ua, 0x07060302u);
}
// truncation pack (1 instr) — for P in the hot loop (values > 0)
__device__ __forceinline__ u32 tpack(float a, float b) {
  return __builtin_amdgcn_perm(__float_as_uint(b), __float_as_uint(a), 0x07060302u);
}

// async global->LDS, 16B per lane. LDS dest is wave-uniform base; HW adds lane*16.
__device__ __forceinline__ void async_copy16(const u16* g, const u16* lds_uniform_base) {
  __builtin_amdgcn_global_load_lds(
      (const __attribute__((address_space(1))) unsigned int*)(unsigned long long)g,
      (__attribute__((address_space(3))) unsigned int*)(unsigned int)(unsigned long long)lds_uniform_base,
      16, 0, 0);
}

// ---------------- conversion ----------------
__global__ __launch_bounds__(256) void cvt_x(const float* __restrict__ s,
                                             u16* __restrict__ d, int n4) {
  int i = blockIdx.x * 256 + threadIdx.x;
  if (i >= n4) return;
  float4 v = reinterpret_cast<const float4*>(s)[i];
  u16x4 o = { f2bf(v.x), f2bf(v.y), f2bf(v.z), f2bf(v.w) };
  reinterpret_cast<u16x4*>(d)[i] = o;
}

// ---------------- fused weight prep: cvt Wv/Wo + LSR folds (one launch) ----------------
// blocks [0,2048): Wv->Wcat[0,1024), Wo->Wcat[2048,3072) bf16
// blocks [2048,2560): Weffq = foldq * Wq folded by Wql  -> Wcat[1024,1536), beffq
// blocks [2560,3072): Weffk = Wk folded by Wkl          -> Wcat[1536,2048), beffk
__global__ __launch_bounds__(256) void prep_w(const float* __restrict__ Wv,
                                              const float* __restrict__ Wo,
                                              const float* __restrict__ Wq,
                                              const float* __restrict__ bq,
                                              const float* __restrict__ Wql,
                                              const float* __restrict__ Wk,
                                              const float* __restrict__ bk,
                                              const float* __restrict__ Wkl,
                                              u16* __restrict__ Wcat,
                                              float* __restrict__ beffq,
                                              float* __restrict__ beffk) {
  const int tid = threadIdx.x;
  const int bid = blockIdx.x;
  __shared__ float lw[64];
  if (bid < 2048) {
    int i = bid * 256 + tid;
    int reg = i >> 18;
    const float* s = reg ? Wo : Wv;
    int j = i & 262143;
    float4 v = reinterpret_cast<const float4*>(s)[j];
    u16x4 o = { f2bf(v.x), f2bf(v.y), f2bf(v.z), f2bf(v.w) };
    reinterpret_cast<u16x4*>(Wcat)[(reg ? 524288 : 0) + j] = o;
    return;
  }
  const int sel = (bid >= 2560);
  const int hr = bid - (sel ? 2560 : 2048);       // 0..511
  const int h = hr >> 5, r = hr & 31;
  const float* W    = sel ? Wk : Wq;
  const float* bias = sel ? bk : bq;
  const float* lsr  = sel ? Wkl : Wql;
  const float fold  = sel ? 1.0f : 0.25506100790944405f;  // (1/sqrt(32))*log2(e)
  u16*   Weff = Wcat + (sel ? 1572864 : 1048576);
  float* beff = sel ? beffk : beffq;
  if (tid < 64) lw[tid] = lsr[(size_t)(h * 64 + tid) * 32 + r] * fold;
  __syncthreads();
  float a0 = 0.f, a1 = 0.f, a2 = 0.f, a3 = 0.f;
  for (int d = 0; d < 64; d++) {
    float l = lw[d];
    float4 wv = *reinterpret_cast<const float4*>(W + (size_t)(h * 64 + d) * 1024 + tid * 4);
    a0 += l * wv.x; a1 += l * wv.y; a2 += l * wv.z; a3 += l * wv.w;
  }
  u16x4 o = { f2bf(a0), f2bf(a1), f2bf(a2), f2bf(a3) };
  reinterpret_cast<u16x4*>(Weff)[(size_t)hr * 256 + tid] = o;
  if (tid == 0) {
    float s = 0.f;
    for (int d = 0; d < 64; d++) s += lw[d] * bias[h * 64 + d];
    beff[hr] = s;
  }
}

// ---------------- GEMM: C[M,N] = A[M,K] * W[N,K]^T + bias, K=1024 ----------------
// 128x128 tile, BK=64, double-buffered 64KB LDS with XOR-swizzle (slot ^= row&7, T2):
// conflict-free ds_read_b128 (verified: SQ_LDS_BANK_CONFLICT = 0). Stage via
// global_load_lds with PRE-SWIZZLED global source (linear LDS dest, rule #21).
// Plain 2D grid (round-robin XCD on consecutive bm keeps A+W panels L2-resident).
template <int MODE>
__global__ __launch_bounds__(256, 2) void gemm8(const u16* __restrict__ A,
                                                const u16* __restrict__ W,
                                                const float* __restrict__ b0,
                                                const float* __restrict__ b1,
                                                const float* __restrict__ b2,
                                                void* __restrict__ Cv,
                                                u16* __restrict__ qo,
                                                u16* __restrict__ ko,
                                                int ldc) {
  __shared__ __align__(16) u16 Al[2][8192];   // [buf][128 rows][64 k] swizzled
  __shared__ __align__(16) u16 Bl[2][8192];
  const int tid  = threadIdx.x;
  const int lane = tid & 63;
  const int w    = tid >> 6;
  const int quad = lane >> 4;
  const int l16  = lane & 15;
  const int wm   = (w >> 1) << 6;
  const int wn   = (w & 1) << 6;

  const int bm = blockIdx.x << 7;
  const int bn = blockIdx.y << 7;

  const int sr = tid >> 3;
  const int sc = ((tid & 7) ^ (sr & 7)) * 8;
  const u16* Ag = A + (size_t)(bm + sr) * 1024 + sc;
  const u16* Wg = W + (size_t)(bn + sr) * 1024 + sc;

  auto stage = [&](int k0, int bsel) {        // 8 vm ops / tile
#pragma unroll
    for (int j = 0; j < 4; j++)
      async_copy16(Ag + (size_t)j * 32768 + k0, &Al[bsel][j * 2048 + w * 512]);
#pragma unroll
    for (int j = 0; j < 4; j++)
      async_copy16(Wg + (size_t)j * 32768 + k0, &Bl[bsel][j * 2048 + w * 512]);
  };

  int aoff[4], boff[4], sl[2];
#pragma unroll
  for (int mi = 0; mi < 4; mi++) aoff[mi] = (wm + mi * 16 + l16) * 64;
#pragma unroll
  for (int ni = 0; ni < 4; ni++) boff[ni] = (wn + ni * 16 + l16) * 64;
  sl[0] = ((0 + quad) ^ (l16 & 7)) * 8;
  sl[1] = ((4 + quad) ^ (l16 & 7)) * 8;

  floatx4 acc[4][4];
#pragma unroll
  for (int i = 0; i < 4; i++)
#pragma unroll
    for (int j = 0; j < 4; j++) acc[i][j] = (floatx4){0.f, 0.f, 0.f, 0.f};

  stage(0, 0);
  asm volatile("s_waitcnt vmcnt(0)" ::: "memory");
  __builtin_amdgcn_s_barrier();
  asm volatile("" ::: "memory");

  for (int i = 0; i < 16; i++) {
    if (i < 15) stage((i + 1) * 64, (i + 1) & 1);
    const u16* Ab = Al[i & 1];
    const u16* Bb = Bl[i & 1];
#pragma unroll
    for (int ks = 0; ks < 2; ks++) {
      bf16x8 af[4], bfr[4];
#pragma unroll
      for (int mi = 0; mi < 4; mi++)
        af[mi] = *reinterpret_cast<const bf16x8*>(Ab + aoff[mi] + sl[ks]);
#pragma unroll
      for (int ni = 0; ni < 4; ni++)
        bfr[ni] = *reinterpret_cast<const bf16x8*>(Bb + boff[ni] + sl[ks]);
      __builtin_amdgcn_s_setprio(1);
#pragma unroll
      for (int mi = 0; mi < 4; mi++)
#pragma unroll
        for (int ni = 0; ni < 4; ni++)
          acc[mi][ni] = MFMA16(af[mi], bfr[ni], acc[mi][ni]);
      __builtin_amdgcn_s_setprio(0);
    }
    if (i < 15) {
      asm volatile("s_waitcnt vmcnt(0)" ::: "memory");   // tile i+1 landed
      __builtin_amdgcn_s_barrier();
      asm volatile("" ::: "memory");
    }
  }

  if (MODE == 1) {
#pragma unroll
    for (int ni = 0; ni < 4; ni++) {
      int col = bn + wn + ni * 16 + l16;
      float bias = b0[col & 1023];
#pragma unroll
      for (int mi = 0; mi < 4; mi++)
#pragma unroll
        for (int r = 0; r < 4; r++) {
          int row = bm + wm + mi * 16 + quad * 4 + r;
          reinterpret_cast<float*>(Cv)[(size_t)row * ldc + col] = acc[mi][ni][r] + bias;
        }
    }
  } else {
    if (bn < 1024) {
#pragma unroll
      for (int ni = 0; ni < 4; ni++) {
        int col = bn + wn + ni * 16 + l16;
        float bias = b0[col];
#pragma unroll
        for (int mi = 0; mi < 4; mi++)
#pragma unroll
          for (int r = 0; r < 4; r++) {
            int row = bm + wm + mi * 16 + quad * 4 + r;
            reinterpret_cast<u16*>(Cv)[(size_t)row * 1024 + col] =
                f2bf(acc[mi][ni][r] + bias);
          }
      }
    } else {
      u16* outp = (bn < 1536) ? qo : ko;
      const float* bp = (bn < 1536) ? b1 : b2;
#pragma unroll
      for (int ni = 0; ni < 4; ni++) {
        int cc = (bn + wn + ni * 16 + l16) & 511;
        float bias = bp[cc];
        int hh = cc >> 5, rk = cc & 31;
#pragma unroll
        for (int mi = 0; mi < 4; mi++)
#pragma unroll
          for (int r = 0; r < 4; r++) {
            int row = bm + wm + mi * 16 + quad * 4 + r;
            size_t addr =
                ((size_t)((row >> 11) * 16 + hh) * 2048 + (row & 2047)) * 32 + rk;
            outp[addr] = f2bf(acc[mi][ni][r] + bias);
          }
      }
    }
  }
}

// ---------------- V transpose: vt[bh][d][t] ----------------
__global__ __launch_bounds__(256) void vtrans(const u16* __restrict__ V,
                                              u16* __restrict__ vt) {
  const int tb = blockIdx.x;
  const int bh = blockIdx.y;
  const int b = bh >> 4, h = bh & 15;
  __shared__ u16 Vl[64][72];
  const int tid = threadIdx.x;
#pragma unroll
  for (int it = 0; it < 2; it++) {
    int c = it * 256 + tid;
    int t = c >> 3, dc = (c & 7) * 8;
    u16x8 v = *reinterpret_cast<const u16x8*>(
        V + (size_t)(b * T_ + tb * 64 + t) * 1024 + h * 64 + dc);
    *reinterpret_cast<u16x8*>(&Vl[t][dc]) = v;
  }
  __syncthreads();
#pragma unroll
  for (int it = 0; it < 2; it++) {
    int c = it * 256 + tid;
    int d = c >> 3, tt = (c & 7) * 8;
    u16x8 o;
#pragma unroll
    for (int j = 0; j < 8; j++) o[j] = Vl[tt + j][d];
    *reinterpret_cast<u16x8*>(vt + ((size_t)bh * 64 + d) * T_ + tb * 64 + tt) = o;
  }
}

// ---------------- flash attention, QBLK=128, KVBLK=128, register-resident P ----------------
// v5 (latency/sync fix): R5 vs R7 falsified the LDS-BW theory (2x LDS intensity,
// same time) -> limiter is per-step barrier+dependency latency (~1250 cyc/step).
// KVBLK 64->128 halves step count (34->17/block) with 2x work per step (16 MFMA16 +
// 64 exp2 + 64 MFMA1K per wave): stage-at-top of step hides under ~2000cyc compute.
// Double-buffered 48KB LDS (2 blocks/CU). Pattern A: stage(i+1)->buf^1 at top,
// vmcnt(0)+barrier at bottom (WAR-safe: buf^1's readers passed the previous barrier).
// V tile [64 d][128 keys], slot^=(d&15) swizzle (2-way free); K pair-row swizzle
// unchanged (pr&7 == l16>>1). Grid (bh,p): XCD=bh%8, K/V L2-resident (FETCH ~20MB).
__global__ __launch_bounds__(256, 2) void attn(const u16* __restrict__ qlr,
                                               const u16* __restrict__ klr,
                                               const u16* __restrict__ vt,
                                               u16* __restrict__ yatt) {
  const int bh = blockIdx.x;                      // XCD = bh%8 under round-robin
  const int b = bh >> 4, h = bh & 15;
  const int p = blockIdx.y;                       // pair index 0..7
  const int tid = threadIdx.x, lane = tid & 63, w = tid >> 6;
  const int quad = lane >> 4, l16 = lane & 15;

  __shared__ __align__(16) u16 Vt2[2][8192];      // 32 KB: V^T tiles [d=64][128 keys]
  __shared__ __align__(16) u16 Kt2[2][4096];      // 16 KB: K tiles [128 keys][32 rk]

  const u16* qlr_bh = qlr + (size_t)bh * T_ * RK_;
  const u16* klr_bh = klr + (size_t)bh * T_ * RK_;
  const u16* vt_bh  = vt + (size_t)bh * 64 * T_;

  // V read: A-frag (nt 0..7, dt 0..3): d = dt*16+l16, keys nt*16+quad*4..+3.
  // addr = d*128 + ((nt*2+(quad>>1)) ^ (d&15))*8 + (quad&1)*4 ; d&15 == l16 for all dt
  // -> voffN[nt] + dt*2048 (u16), dt part folds into ds_read offset immediate.
  int voffN[8];
#pragma unroll
  for (int nt = 0; nt < 8; nt++)
    voffN[nt] = l16 * 128 + (((nt * 2 + (quad >> 1)) ^ l16) * 8) + (quad & 1) * 4;
  // K read: key k = nt*16+l16, rk slot quad; pair-row pr = k>>1, pr&7 == l16>>1
  const int koff = (l16 >> 1) * 64 + ((((l16 & 1) * 4 + quad) ^ (l16 >> 1)) * 8);

  // V staging (4 issues): LDS linear L = it*256+tid -> d = L>>4, slot = L&15;
  // source pre-swizzled: src slot = slot ^ (d&15)
  int soffV[4];
#pragma unroll
  for (int it = 0; it < 4; it++) {
    int L = it * 256 + tid;
    int d = L >> 4, s = L & 15;
    soffV[it] = d * T_ + ((s ^ (d & 15)) * 8);
  }
  // K staging (2 issues): L -> pr = L>>3, slot = L&7; src slot = slot ^ (pr&7)
  int soffK[2];
#pragma unroll
  for (int it = 0; it < 2; it++) {
    int L = it * 256 + tid;
    int pr = L >> 3, s = L & 7;
    soffK[it] = pr * 64 + ((s ^ (pr & 7)) * 8);
  }
  const int wub = w * 512;

  const floatx4 fzero = {0.f, 0.f, 0.f, 0.f};
  const int thrq = w * 16 + l16;                  // local-64 q index owned by lane

  for (int run = 0; run < 2; run++) {
    const int j = run ? p : 15 - p;               // heavy q-tile first
    const int q0 = j << 7;
    const int nkt = j + 1;                        // 128-key tiles (last = diagonal)

    bf16x8 qf[2];
#pragma unroll
    for (int qg = 0; qg < 2; qg++)
      qf[qg] = *reinterpret_cast<const bf16x8*>(
          qlr_bh + (size_t)(q0 + qg * 64 + thrq) * 32 + quad * 8);

    auto stage = [&](int t, int bi) {             // 6 vm ops per wave
#pragma unroll
      for (int it = 0; it < 4; it++)
        async_copy16(vt_bh + t * 128 + soffV[it], &Vt2[bi][it * 2048 + wub]);
#pragma unroll
      for (int it = 0; it < 2; it++)
        async_copy16(klr_bh + t * 4096 + soffK[it], &Kt2[bi][it * 2048 + wub]);
    };

    stage(0, 0);                                  // WAR-safe: prior step's barrier passed
    asm volatile("s_waitcnt vmcnt(0)" ::: "memory");
    __builtin_amdgcn_s_barrier();
    asm volatile("" ::: "memory");

    floatx4 oacc[4][2];                           // [dt][qg]
#pragma unroll
    for (int i = 0; i < 4; i++)
#pragma unroll
      for (int jg = 0; jg < 2; jg++) oacc[i][jg] = fzero;
    float rs[2] = {0.f, 0.f};

    for (int i = 0; i < nkt; i++) {
      const bool last = (i == nkt - 1);
      if (!last) stage(i + 1, (i + 1) & 1);
      const u16* Vb = &Vt2[i & 1][0];
      const u16* Kb = &Kt2[i & 1][0];

      bf16x8 kf[8];
#pragma unroll
      for (int nt = 0; nt < 8; nt++)
        kf[nt] = *reinterpret_cast<const bf16x8*>(Kb + koff + nt * 512);

      uint2 pk[8][2];
      if (!last) {
#pragma unroll
        for (int qg = 0; qg < 2; qg++) {
          __builtin_amdgcn_s_setprio(1);
          floatx4 sv[8];
#pragma unroll
          for (int nt = 0; nt < 8; nt++) sv[nt] = MFMA16(kf[nt], qf[qg], fzero);
          __builtin_amdgcn_s_setprio(0);
#pragma unroll
          for (int nt = 0; nt < 8; nt++) {
            float p0 = __builtin_amdgcn_exp2f(sv[nt][0]);
            float p1 = __builtin_amdgcn_exp2f(sv[nt][1]);
            float p2 = __builtin_amdgcn_exp2f(sv[nt][2]);
            float p3 = __builtin_amdgcn_exp2f(sv[nt][3]);
            rs[qg] += (p0 + p1) + (p2 + p3);
            pk[nt][qg].x = tpack(p0, p1);
            pk[nt][qg].y = tpack(p2, p3);
          }
        }
      } else {
        // diagonal: key local kl = nt*16+quad*4+r vs q local thr = qg*64+thrq
#pragma unroll
        for (int qg = 0; qg < 2; qg++) {
          const int thr = qg * 64 + thrq;
#pragma unroll
          for (int nt = 0; nt < 8; nt++) {
            floatx4 sv = MFMA16(kf[nt], qf[qg], fzero);
            const int keyl = nt * 16 + quad * 4;
            float pr[4];
#pragma unroll
            for (int r = 0; r < 4; r++) {
              float e = __builtin_amdgcn_exp2f(sv[r]);
              pr[r] = (keyl + r <= thr) ? e : 0.f;
            }
            rs[qg] += (pr[0] + pr[1]) + (pr[2] + pr[3]);
            pk[nt][qg].x = tpack(pr[0], pr[1]);
            pk[nt][qg].y = tpack(pr[2], pr[3]);
          }
        }
      }

      __builtin_amdgcn_s_setprio(1);
#pragma unroll
      for (int dt = 0; dt < 4; dt++)
#pragma unroll
        for (int nt = 0; nt < 8; nt++) {
          s16x4 vf = *reinterpret_cast<const s16x4*>(Vb + voffN[nt] + dt * 2048);
          oacc[dt][0] = MFMA1K(vf, __builtin_bit_cast(s16x4, pk[nt][0]), oacc[dt][0]);
          oacc[dt][1] = MFMA1K(vf, __builtin_bit_cast(s16x4, pk[nt][1]), oacc[dt][1]);
        }
      __builtin_amdgcn_s_setprio(0);

      asm volatile("s_waitcnt vmcnt(0)" ::: "memory");   // staged tile i+1 landed
      __builtin_amdgcn_s_barrier();
      asm volatile("" ::: "memory");
    }

    // row-sum across the 4 quads; normalize; store O^T (d = dt*16+quad*4+r)
#pragma unroll
    for (int qg = 0; qg < 2; qg++) {
      rs[qg] += __shfl_xor(rs[qg], 16);
      rs[qg] += __shfl_xor(rs[qg], 32);
    }
#pragma unroll
    for (int qg = 0; qg < 2; qg++) {
      float inv = 1.f / rs[qg];
      const int qrow = q0 + qg * 64 + thrq;
#pragma unroll
      for (int dt = 0; dt < 4; dt++) {
        uint2 ov = { pack_bf(oacc[dt][qg][0] * inv, oacc[dt][qg][1] * inv),
                     pack_bf(oacc[dt][qg][2] * inv, oacc[dt][qg][3] * inv) };
        *reinterpret_cast<uint2*>(
            yatt + (size_t)(b * T_ + qrow) * 1024 + h * 64 + dt * 16 + quad * 4) = ov;
      }
    }
  }
}

// ---------------- launch ----------------
extern "C" void kernel_launch(void* const* d_in, const int* in_sizes, int n_in,
                              void* d_out, int out_size, void* d_ws, size_t ws_size,
                              hipStream_t stream) {
  const float* x   = (const float*)d_in[0];
  const float* Wq  = (const float*)d_in[1];
  const float* bq  = (const float*)d_in[2];
  const float* Wk  = (const float*)d_in[3];
  const float* bk  = (const float*)d_in[4];
  const float* Wv  = (const float*)d_in[5];
  const float* bv  = (const float*)d_in[6];
  const float* Wo  = (const float*)d_in[7];
  const float* bo  = (const float*)d_in[8];
  const float* Wql = (const float*)d_in[9];
  const float* Wkl = (const float*)d_in[10];
  float* out = (float*)d_out;

  char* ws = (char*)d_ws;
  u16*   xb    = (u16*)(ws);                  // 8192x1024 bf16 (16 MB) -- reused as vt
  u16*   Wcat  = (u16*)(ws + 16777216);       // 3072x1024 bf16 (6 MB): Wv | Weffq | Weffk | Wo
  float* beffq = (float*)(ws + 23068672);     // 512 f32
  float* beffk = (float*)(ws + 23072768);     // 512 f32
  u16*   Vbuf  = (u16*)(ws + 25165824);       // 8192x1024 bf16 (16 MB)
  u16*   qlr   = (u16*)(ws + 41943040);       // 64x2048x32 bf16 (8 MB)
  u16*   klr   = (u16*)(ws + 50331648);       // 64x2048x32 bf16 (8 MB)
  u16*   yatt  = (u16*)(ws + 58720256);       // 8192x1024 bf16 (16 MB)
  u16*   vt    = xb;                          // [bh][64][2048] bf16, after gemm0

  cvt_x<<<dim3(8192), 256, 0, stream>>>(x, xb, 2097152);
  prep_w<<<dim3(3072), 256, 0, stream>>>(Wv, Wo, Wq, bq, Wql, Wk, bk, Wkl,
                                         Wcat, beffq, beffk);
  gemm8<2><<<dim3(64, 16), 256, 0, stream>>>(xb, Wcat, bv, beffq, beffk,
                                             Vbuf, qlr, klr, 0);
  vtrans<<<dim3(32, 64), 256, 0, stream>>>(Vbuf, vt);
  attn<<<dim3(64, 8), 256, 0, stream>>>(qlr, klr, vt, yatt);
  gemm8<1><<<dim3(64, 8), 256, 0, stream>>>(yatt, Wcat + 2097152, bo, bo, bo,
                                            out, nullptr, nullptr, 1024);
}